// Round 2
// baseline (178.014 us; speedup 1.0000x reference)
//
#include <hip/hip_runtime.h>
#include <hip/hip_cooperative_groups.h>
#include <math.h>

namespace cg = cooperative_groups;

// Problem constants (fixed by setup_inputs): B=2, S=2048, D=128, NH=8, NB=32
constexpr int B = 2;
constexpr int S = 2048;
constexpr int D = 128;
constexpr int NH = 8;
constexpr int NK = 16;          // num_buckets / 2
constexpr int NB = 32;          // num_buckets
constexpr float EPS = 1e-5f;
constexpr float SCALE = 0.08838834764831845f;  // 1/sqrt(128)

constexpr int MAXN = 192;       // max bucket size (binomial mean 64, sigma ~7.9 -> 12 sigma)
constexpr int KP   = 136;       // Kb row pitch in bf16 elems (128 + 8, keeps 16B alignment)
constexpr int TP   = 200;       // w/Pt row pitch (192 + 8)
constexpr int QSPLIT = 8;       // blocks per bucket (split over query tiles)
constexpr int GRID  = B * NB * QSPLIT;   // 512 = 2 blocks/CU on 256 CUs (co-residency proof:
                                         // LDS 70.6KB<=80KB, launch_bounds(256,2) -> <=128 VGPR)

typedef __attribute__((ext_vector_type(8))) short bf16x8;
typedef __attribute__((ext_vector_type(4))) float f32x4;

__device__ __forceinline__ ushort f2bf(float f) {
    uint u = __float_as_uint(f);
    u += 0x7FFFu + ((u >> 16) & 1u);     // round-to-nearest-even
    return (ushort)(u >> 16);
}

// ---------------------------------------------------------------------------
// Fused kernel: phase 1 (LayerNorm + last-round LSH hash) -> grid.sync() ->
// phase 2 (bucket-centric MFMA attention). One dispatch instead of two:
// removes a kernel launch + the full inter-kernel drain (K2's first load
// depends on the last K1 store).
//
// Phase 2 notes (unchanged from the previous round's attn_kernel):
//  - 70.6 KB LDS -> 2 blocks/CU co-resident.
//  - No KT transpose: PV B-fragment gathers K columns from row-major Kb.
//  - Exact fp32 diagonal fused into the Gram epilogue.
//  - Wave-local softmax (16-lane groups, shfl_xor, no barriers inside).
//  - Compaction is DETERMINISTIC + ORDERED so all QSPLIT blocks of one
//    bucket agree on idx[] and partition the query tiles exactly.
// ---------------------------------------------------------------------------
__global__ __launch_bounds__(256, 2) void fused_kernel(
    const float* __restrict__ x, const float* __restrict__ mask,
    const float* __restrict__ rot, ushort* __restrict__ xmb,
    int* __restrict__ bucket, float* __restrict__ selfp,
    float* __restrict__ out)
{
    const int tid  = threadIdx.x;
    const int lane = tid & 63;
    const int wave = tid >> 6;

    // ======================= phase 1: LN + hash ==========================
    // 512 blocks x 4 waves x 2 rows = 4096 rows. One WAVE per row, zero
    // barriers; single-pass moments (fused sum/sumsq butterfly).
    #pragma unroll
    for (int rr = 0; rr < 2; ++rr) {
        const int row = blockIdx.x * 8 + wave * 2 + rr;
        const int b   = row >> 11;                   // row / S

        const float v0 = x[(size_t)row * D + lane];
        const float v1 = x[(size_t)row * D + lane + 64];

        float s  = v0 + v1;
        float s2 = v0 * v0 + v1 * v1;
        #pragma unroll
        for (int off = 32; off > 0; off >>= 1) {
            s  += __shfl_xor(s,  off, 64);
            s2 += __shfl_xor(s2, off, 64);
        }
        const float mu      = s * (1.0f / 128.0f);
        const float central = s2 - 128.0f * mu * mu;      // == sum((x-mu)^2)
        const float rstd    = 1.0f / sqrtf(central * (1.0f / 128.0f) + EPS);

        const float xn0 = (v0 - mu) * rstd, xn1 = (v1 - mu) * rstd;
        const float mk = mask[row];
        xmb[(size_t)row * D + lane]      = f2bf(xn0 * mk);
        xmb[(size_t)row * D + lane + 64] = f2bf(xn1 * mk);

        // projection (last hash round only): rk = sum_d xn[d]*R[b,d,NH-1,k]
        const float4* r0 = (const float4*)(rot + (((size_t)(b * D + lane)) * NH + (NH - 1)) * NK);
        const float4* r1 = (const float4*)(rot + (((size_t)(b * D + lane + 64)) * NH + (NH - 1)) * NK);
        float racc[NK];
        #pragma unroll
        for (int q = 0; q < 4; ++q) {
            const float4 a = r0[q];
            const float4 c = r1[q];
            racc[q * 4 + 0] = xn0 * a.x + xn1 * c.x;
            racc[q * 4 + 1] = xn0 * a.y + xn1 * c.y;
            racc[q * 4 + 2] = xn0 * a.z + xn1 * c.z;
            racc[q * 4 + 3] = xn0 * a.w + xn1 * c.w;
        }
        #pragma unroll
        for (int k = 0; k < NK; ++k) {
            float t = racc[k];
            #pragma unroll
            for (int off = 32; off > 0; off >>= 1) t += __shfl_xor(t, off, 64);
            racc[k] = t;
        }

        // argmax over [rot, -rot], first-max semantics
        float best = racc[0]; int bi = 0;
        #pragma unroll
        for (int k = 1; k < NK; ++k) if (racc[k] > best) { best = racc[k]; bi = k; }
        #pragma unroll
        for (int k = 0; k < NK; ++k) if (-racc[k] > best) { best = -racc[k]; bi = k + NK; }

        if (lane == 0) {
            bucket[row] = bi;
            // exact self score: scale * ||xn*mk||^2
            selfp[row] = SCALE * central * rstd * rstd * mk * mk;
        }
    }

    // ============ grid-wide sync (release -> barrier -> acquire) =========
    __threadfence();            // agent-scope release: push xmb/bucket/self to device visibility
    cg::this_grid().sync();
    __threadfence();            // acquire side: invalidate L1/L2 before cross-XCD reads

    // ======================= phase 2: attention ==========================
    const int bg   = blockIdx.x >> 3;     // bucket global id 0..63
    const int qs   = blockIdx.x & 7;      // query-tile split
    const int b    = bg >> 5;
    const int beta = bg & 31;
    const int col  = lane & 15;           // MFMA n/col index
    const int quad = lane >> 4;           // MFMA k-group

    __shared__ __align__(16) ushort Kb[MAXN * KP];    // keys, row-major bf16 (52.2 KB)
    __shared__ __align__(16) float  w[16 * TP];       // fp32 scores, one qtile (12.8 KB)
    __shared__ __align__(16) ushort Pt[16 * TP];      // bf16 exp weights (6.4 KB)
    __shared__ int   idx[MAXN];
    __shared__ float invrow[16];
    __shared__ int   wsum[4];

    // --- deterministic ordered compaction: thread tid owns rows [tid*8, tid*8+8) ---
    const int base = b * S;
    const int4* bp = (const int4*)(bucket + base);
    const int4 u0 = bp[tid * 2];
    const int4 u1 = bp[tid * 2 + 1];
    int m0 = (u0.x == beta) | ((u0.y == beta) << 1) | ((u0.z == beta) << 2) |
             ((u0.w == beta) << 3) | ((u1.x == beta) << 4) | ((u1.y == beta) << 5) |
             ((u1.z == beta) << 6) | ((u1.w == beta) << 7);
    const int cntl = __popc(m0);

    int inc = cntl;                       // wave-level inclusive scan
    #pragma unroll
    for (int off = 1; off < 64; off <<= 1) {
        const int t = __shfl_up(inc, off, 64);
        if (lane >= off) inc += t;
    }
    if (lane == 63) wsum[wave] = inc;
    __syncthreads();
    int start = inc - cntl;
    #pragma unroll
    for (int wv = 0; wv < 4; ++wv) if (wv < wave) start += wsum[wv];
    const int ntot = wsum[0] + wsum[1] + wsum[2] + wsum[3];
    const int n = min(ntot, MAXN);

    // early out: this block's query-tile split is empty (uniform condition)
    if (qs * 16 >= n) return;

    {
        const int t0 = tid * 8;
        int p = start;
        #pragma unroll
        for (int k = 0; k < 8; ++k)
            if ((m0 >> k) & 1) { if (p < MAXN) idx[p] = t0 + k; ++p; }
    }
    __syncthreads();
    const int npad32 = (n + 31) & ~31;

    // --- stage keys into LDS (bf16, row-major, padded pitch) ---
    for (int c = tid; c < n * 16; c += 256) {
        const int i = c >> 4, ch = c & 15;
        *(bf16x8*)&Kb[i * KP + ch * 8] =
            *(const bf16x8*)(xmb + (size_t)(base + idx[i]) * D + ch * 8);
    }
    // zero rows [n, npad32): A/B operands of Gram and B of PV read them
    {
        const bf16x8 z = {0, 0, 0, 0, 0, 0, 0, 0};
        for (int e = tid; e < 32 * 16; e += 256) {
            const int j = n + (e >> 4), ch = e & 15;
            if (j < npad32) *(bf16x8*)&Kb[j * KP + ch * 8] = z;
        }
    }
    // zero Pt pad cols [n, npad32) once; softmax only writes j < n
    for (int e = tid; e < 16 * 32; e += 256) {
        const int r = e >> 5, j = n + (e & 31);
        if (j < npad32) Pt[r * TP + j] = 0;
    }
    __syncthreads();

    // --- query-tile loop (strided over QSPLIT blocks; all blocks agree on idx) ---
    for (int qt = qs; qt * 16 < n; qt += QSPLIT) {
        const int q0 = qt * 16;
        const int rows = min(16, n - q0);

        // Gram: C[i][j] = sum_d K[q0+i][d] * K[J0+j][d], per-wave over key tiles.
        // Exact fp32 diagonal patched in-register by the kt==qt wave.
        for (int kt = wave; kt * 16 < n; kt += 4) {
            const int J0 = kt * 16;
            f32x4 acc = {0.f, 0.f, 0.f, 0.f};
            #pragma unroll
            for (int ks = 0; ks < 4; ++ks) {
                const bf16x8 a  = *(const bf16x8*)&Kb[(q0 + col) * KP + quad * 8 + ks * 32];
                const bf16x8 bb = *(const bf16x8*)&Kb[(J0 + col) * KP + quad * 8 + ks * 32];
                acc = __builtin_amdgcn_mfma_f32_16x16x32_bf16(a, bb, acc, 0, 0, 0);
            }
            float selfv = 0.0f;
            if (J0 == q0 && q0 + col < n) selfv = selfp[base + idx[q0 + col]];
            #pragma unroll
            for (int r = 0; r < 4; ++r) {
                const int i = quad * 4 + r;
                float v = acc[r] * SCALE;
                if (J0 == q0 && col == i) v = selfv;   // exact diagonal
                w[i * TP + J0 + col] = v;
            }
        }
        __syncthreads();

        // wave-local softmax: 16-lane group (quad) of each wave owns one row
        {
            const int r = wave * 4 + quad;       // 4 waves x 4 groups = 16 rows
            const int g = col;
            float pm = 0.0f;   // the S-n zero scores floor the max at 0
            if (r < rows)
                for (int j = g; j < n; j += 16) pm = fmaxf(pm, w[r * TP + j]);
            #pragma unroll
            for (int off = 8; off > 0; off >>= 1) pm = fmaxf(pm, __shfl_xor(pm, off, 16));
            float ps = 0.0f;
            if (r < rows) {
                for (int j = g; j < n; j += 16) {
                    const float e = __expf(w[r * TP + j] - pm);
                    Pt[r * TP + j] = f2bf(e);
                    ps += e;
                }
            }
            #pragma unroll
            for (int off = 8; off > 0; off >>= 1) ps += __shfl_xor(ps, off, 16);
            if (r < rows && g == 0)
                invrow[r] = 1.0f / (ps + (float)(S - n) * __expf(-pm));
        }
        __syncthreads();

        // PV: O[i][d] = sum_j P[i][j] * K[j][d].
        // B-fragment = column (dt*16+col) of row-major Kb, 8 scalar u16 reads.
        for (int dt = wave; dt < 8; dt += 4) {
            f32x4 acc = {0.f, 0.f, 0.f, 0.f};
            for (int ks = 0; ks < npad32 / 32; ++ks) {
                const bf16x8 a = *(const bf16x8*)&Pt[col * TP + ks * 32 + quad * 8];
                bf16x8 bb;
                #pragma unroll
                for (int e = 0; e < 8; ++e)
                    bb[e] = (short)Kb[(ks * 32 + quad * 8 + e) * KP + dt * 16 + col];
                acc = __builtin_amdgcn_mfma_f32_16x16x32_bf16(a, bb, acc, 0, 0, 0);
            }
            #pragma unroll
            for (int r = 0; r < 4; ++r) {
                const int rr = quad * 4 + r;
                if (rr < rows)
                    out[(size_t)(base + idx[q0 + rr]) * D + dt * 16 + col] =
                        acc[r] * invrow[rr];
            }
        }
        __syncthreads();   // before next qtile reuses w/Pt
    }
}

// ---------------------------------------------------------------------------
extern "C" void kernel_launch(void* const* d_in, const int* in_sizes, int n_in,
                              void* d_out, int out_size, void* d_ws, size_t ws_size,
                              hipStream_t stream) {
    const float* x    = (const float*)d_in[0];   // (B,S,D) fp32
    const float* mask = (const float*)d_in[1];   // (B,S) fp32
    const float* rot  = (const float*)d_in[2];   // (B,D,NH,NK) fp32

    char* ws = (char*)d_ws;
    ushort* xmb  = (ushort*)ws;                  ws += (size_t)B * S * D * sizeof(ushort); // 1 MB
    int*    bkt  = (int*)ws;                     ws += (size_t)B * S * sizeof(int);        // 16 KB
    float*  self = (float*)ws;                                                             // 16 KB
    float*  out  = (float*)d_out;

    void* args[] = { (void*)&x, (void*)&mask, (void*)&rot,
                     (void*)&xmb, (void*)&bkt, (void*)&self, (void*)&out };
    hipLaunchCooperativeKernel((const void*)fused_kernel, dim3(GRID), dim3(256),
                               args, 0, stream);
}

// Round 3
// 75.842 us; speedup vs baseline: 2.3472x; 2.3472x over previous
//
#include <hip/hip_runtime.h>
#include <math.h>

// Problem constants (fixed by setup_inputs): B=2, S=2048, D=128, NH=8, NB=32
constexpr int B = 2;
constexpr int S = 2048;
constexpr int D = 128;
constexpr int NH = 8;
constexpr int NK = 16;          // num_buckets / 2
constexpr int NB = 32;          // num_buckets
constexpr float EPS = 1e-5f;
constexpr float SCALE = 0.08838834764831845f;  // 1/sqrt(128)

constexpr int MAXN = 192;       // max bucket size (binomial mean 64, sigma ~7.9 -> 12 sigma)
constexpr int KP   = 136;       // Kb row pitch in bf16 elems (128 + 8, keeps 16B alignment)
constexpr int TP   = 200;       // w/Pt row pitch (192 + 8)
constexpr int QSPLIT = 8;       // blocks per bucket (split over query tiles)
                                // 8 -> grid 512 -> 2 blocks/CU (needs <=80KB LDS/block)

typedef __attribute__((ext_vector_type(8))) short bf16x8;
typedef __attribute__((ext_vector_type(4))) float f32x4;

__device__ __forceinline__ ushort f2bf(float f) {
    uint u = __float_as_uint(f);
    u += 0x7FFFu + ((u >> 16) & 1u);     // round-to-nearest-even
    return (ushort)(u >> 16);
}

// ---------------------------------------------------------------------------
// K1: LayerNorm + last-round LSH hash, one WAVE per row, zero barriers.
// Single-pass moments (sum, sumsq in one interleaved butterfly).
// Emits: xmb (bf16 xm), bucket id, exact fp32 self-score scale*||xm||^2.
// ---------------------------------------------------------------------------
__global__ __launch_bounds__(256) void ln_hash_kernel(
    const float* __restrict__ x, const float* __restrict__ mask,
    const float* __restrict__ rot, ushort* __restrict__ xmb,
    int* __restrict__ bucket, float* __restrict__ selfp)
{
    const int wave = threadIdx.x >> 6;
    const int lane = threadIdx.x & 63;
    const int row  = blockIdx.x * 4 + wave;       // grid = B*S/4 blocks
    const int b    = row >> 11;                   // row / S

    const float v0 = x[(size_t)row * D + lane];
    const float v1 = x[(size_t)row * D + lane + 64];

    // fused sum / sumsq butterfly (independent chains -> ILP)
    float s  = v0 + v1;
    float s2 = v0 * v0 + v1 * v1;
    #pragma unroll
    for (int off = 32; off > 0; off >>= 1) {
        s  += __shfl_xor(s,  off, 64);
        s2 += __shfl_xor(s2, off, 64);
    }
    const float mu      = s * (1.0f / 128.0f);
    const float central = s2 - 128.0f * mu * mu;          // == sum((x-mu)^2)
    const float rstd    = 1.0f / sqrtf(central * (1.0f / 128.0f) + EPS);

    const float xn0 = (v0 - mu) * rstd, xn1 = (v1 - mu) * rstd;
    const float mk = mask[row];
    xmb[(size_t)row * D + lane]      = f2bf(xn0 * mk);
    xmb[(size_t)row * D + lane + 64] = f2bf(xn1 * mk);

    // projection (last hash round only): rk = sum_d xn[d]*R[b,d,NH-1,k]
    const float4* r0 = (const float4*)(rot + (((size_t)(b * D + lane)) * NH + (NH - 1)) * NK);
    const float4* r1 = (const float4*)(rot + (((size_t)(b * D + lane + 64)) * NH + (NH - 1)) * NK);
    float racc[NK];
    #pragma unroll
    for (int q = 0; q < 4; ++q) {
        const float4 a = r0[q];
        const float4 c = r1[q];
        racc[q * 4 + 0] = xn0 * a.x + xn1 * c.x;
        racc[q * 4 + 1] = xn0 * a.y + xn1 * c.y;
        racc[q * 4 + 2] = xn0 * a.z + xn1 * c.z;
        racc[q * 4 + 3] = xn0 * a.w + xn1 * c.w;
    }
    #pragma unroll
    for (int k = 0; k < NK; ++k) {
        float t = racc[k];
        #pragma unroll
        for (int off = 32; off > 0; off >>= 1) t += __shfl_xor(t, off, 64);
        racc[k] = t;
    }

    // argmax over [rot, -rot], first-max semantics
    float best = racc[0]; int bi = 0;
    #pragma unroll
    for (int k = 1; k < NK; ++k) if (racc[k] > best) { best = racc[k]; bi = k; }
    #pragma unroll
    for (int k = 0; k < NK; ++k) if (-racc[k] > best) { best = -racc[k]; bi = k + NK; }

    if (lane == 0) {
        bucket[row] = bi;
        // exact self score: scale * ||xn*mk||^2
        selfp[row] = SCALE * central * rstd * rstd * mk * mk;
    }
}

// ---------------------------------------------------------------------------
// K2: bucket-centric MFMA attention. Grid = B*NB*QSPLIT = 512 blocks.
//  - 70.6 KB LDS -> 2 blocks/CU co-resident (latency hiding).
//  - No KT transpose: PV B-fragment gathers K columns from row-major Kb.
//  - Exact fp32 diagonal fused into the Gram epilogue.
//  - Wave-local softmax (16-lane groups, shfl_xor, no barriers inside).
// Compaction is DETERMINISTIC + ORDERED so all QSPLIT blocks of one bucket
// agree on idx[] and partition the query tiles exactly.
// ---------------------------------------------------------------------------
__global__ __launch_bounds__(256, 2) void attn_kernel(
    const ushort* __restrict__ xmb, const int* __restrict__ bucket,
    const float* __restrict__ selfp, float* __restrict__ out)
{
    const int bg   = blockIdx.x >> 3;     // bucket global id 0..63
    const int qs   = blockIdx.x & 7;      // query-tile split
    const int b    = bg >> 5;
    const int beta = bg & 31;
    const int tid  = threadIdx.x;
    const int lane = tid & 63;
    const int wave = tid >> 6;
    const int col  = lane & 15;           // MFMA n/col index
    const int quad = lane >> 4;           // MFMA k-group

    __shared__ __align__(16) ushort Kb[MAXN * KP];    // keys, row-major bf16 (52.2 KB)
    __shared__ __align__(16) float  w[16 * TP];       // fp32 scores, one qtile (12.8 KB)
    __shared__ __align__(16) ushort Pt[16 * TP];      // bf16 exp weights (6.4 KB)
    __shared__ int   idx[MAXN];
    __shared__ float invrow[16];
    __shared__ int   wsum[4];

    // --- deterministic ordered compaction: thread tid owns rows [tid*8, tid*8+8) ---
    const int base = b * S;
    const int4* bp = (const int4*)(bucket + base);
    const int4 u0 = bp[tid * 2];
    const int4 u1 = bp[tid * 2 + 1];
    int m0 = (u0.x == beta) | ((u0.y == beta) << 1) | ((u0.z == beta) << 2) |
             ((u0.w == beta) << 3) | ((u1.x == beta) << 4) | ((u1.y == beta) << 5) |
             ((u1.z == beta) << 6) | ((u1.w == beta) << 7);
    const int cntl = __popc(m0);

    int inc = cntl;                       // wave-level inclusive scan
    #pragma unroll
    for (int off = 1; off < 64; off <<= 1) {
        const int t = __shfl_up(inc, off, 64);
        if (lane >= off) inc += t;
    }
    if (lane == 63) wsum[wave] = inc;
    __syncthreads();
    int start = inc - cntl;
    #pragma unroll
    for (int wv = 0; wv < 4; ++wv) if (wv < wave) start += wsum[wv];
    const int ntot = wsum[0] + wsum[1] + wsum[2] + wsum[3];
    const int n = min(ntot, MAXN);

    // early out: this block's query-tile split is empty (uniform condition)
    if (qs * 16 >= n) return;

    {
        const int t0 = tid * 8;
        int p = start;
        #pragma unroll
        for (int k = 0; k < 8; ++k)
            if ((m0 >> k) & 1) { if (p < MAXN) idx[p] = t0 + k; ++p; }
    }
    __syncthreads();
    const int npad32 = (n + 31) & ~31;

    // --- stage keys into LDS (bf16, row-major, padded pitch) ---
    for (int c = tid; c < n * 16; c += 256) {
        const int i = c >> 4, ch = c & 15;
        *(bf16x8*)&Kb[i * KP + ch * 8] =
            *(const bf16x8*)(xmb + (size_t)(base + idx[i]) * D + ch * 8);
    }
    // zero rows [n, npad32): A/B operands of Gram and B of PV read them
    {
        const bf16x8 z = {0, 0, 0, 0, 0, 0, 0, 0};
        for (int e = tid; e < 32 * 16; e += 256) {
            const int j = n + (e >> 4), ch = e & 15;
            if (j < npad32) *(bf16x8*)&Kb[j * KP + ch * 8] = z;
        }
    }
    // zero Pt pad cols [n, npad32) once; softmax only writes j < n
    for (int e = tid; e < 16 * 32; e += 256) {
        const int r = e >> 5, j = n + (e & 31);
        if (j < npad32) Pt[r * TP + j] = 0;
    }
    __syncthreads();

    // --- query-tile loop (strided over QSPLIT blocks; all blocks agree on idx) ---
    for (int qt = qs; qt * 16 < n; qt += QSPLIT) {
        const int q0 = qt * 16;
        const int rows = min(16, n - q0);

        // Gram: C[i][j] = sum_d K[q0+i][d] * K[J0+j][d], per-wave over key tiles.
        // Exact fp32 diagonal patched in-register by the kt==qt wave.
        for (int kt = wave; kt * 16 < n; kt += 4) {
            const int J0 = kt * 16;
            f32x4 acc = {0.f, 0.f, 0.f, 0.f};
            #pragma unroll
            for (int ks = 0; ks < 4; ++ks) {
                const bf16x8 a  = *(const bf16x8*)&Kb[(q0 + col) * KP + quad * 8 + ks * 32];
                const bf16x8 bb = *(const bf16x8*)&Kb[(J0 + col) * KP + quad * 8 + ks * 32];
                acc = __builtin_amdgcn_mfma_f32_16x16x32_bf16(a, bb, acc, 0, 0, 0);
            }
            float selfv = 0.0f;
            if (J0 == q0 && q0 + col < n) selfv = selfp[base + idx[q0 + col]];
            #pragma unroll
            for (int r = 0; r < 4; ++r) {
                const int i = quad * 4 + r;
                float v = acc[r] * SCALE;
                if (J0 == q0 && col == i) v = selfv;   // exact diagonal
                w[i * TP + J0 + col] = v;
            }
        }
        __syncthreads();

        // wave-local softmax: 16-lane group (quad) of each wave owns one row
        {
            const int r = wave * 4 + quad;       // 4 waves x 4 groups = 16 rows
            const int g = col;
            float pm = 0.0f;   // the S-n zero scores floor the max at 0
            if (r < rows)
                for (int j = g; j < n; j += 16) pm = fmaxf(pm, w[r * TP + j]);
            #pragma unroll
            for (int off = 8; off > 0; off >>= 1) pm = fmaxf(pm, __shfl_xor(pm, off, 16));
            float ps = 0.0f;
            if (r < rows) {
                for (int j = g; j < n; j += 16) {
                    const float e = __expf(w[r * TP + j] - pm);
                    Pt[r * TP + j] = f2bf(e);
                    ps += e;
                }
            }
            #pragma unroll
            for (int off = 8; off > 0; off >>= 1) ps += __shfl_xor(ps, off, 16);
            if (r < rows && g == 0)
                invrow[r] = 1.0f / (ps + (float)(S - n) * __expf(-pm));
        }
        __syncthreads();

        // PV: O[i][d] = sum_j P[i][j] * K[j][d].
        // B-fragment = column (dt*16+col) of row-major Kb, 8 scalar u16 reads.
        for (int dt = wave; dt < 8; dt += 4) {
            f32x4 acc = {0.f, 0.f, 0.f, 0.f};
            for (int ks = 0; ks < npad32 / 32; ++ks) {
                const bf16x8 a = *(const bf16x8*)&Pt[col * TP + ks * 32 + quad * 8];
                bf16x8 bb;
                #pragma unroll
                for (int e = 0; e < 8; ++e)
                    bb[e] = (short)Kb[(ks * 32 + quad * 8 + e) * KP + dt * 16 + col];
                acc = __builtin_amdgcn_mfma_f32_16x16x32_bf16(a, bb, acc, 0, 0, 0);
            }
            #pragma unroll
            for (int r = 0; r < 4; ++r) {
                const int rr = quad * 4 + r;
                if (rr < rows)
                    out[(size_t)(base + idx[q0 + rr]) * D + dt * 16 + col] =
                        acc[r] * invrow[rr];
            }
        }
        __syncthreads();   // before next qtile reuses w/Pt
    }
}

// ---------------------------------------------------------------------------
extern "C" void kernel_launch(void* const* d_in, const int* in_sizes, int n_in,
                              void* d_out, int out_size, void* d_ws, size_t ws_size,
                              hipStream_t stream) {
    const float* x    = (const float*)d_in[0];   // (B,S,D) fp32
    const float* mask = (const float*)d_in[1];   // (B,S) fp32
    const float* rot  = (const float*)d_in[2];   // (B,D,NH,NK) fp32

    char* ws = (char*)d_ws;
    ushort* xmb  = (ushort*)ws;                  ws += (size_t)B * S * D * sizeof(ushort); // 1 MB
    int*    bkt  = (int*)ws;                     ws += (size_t)B * S * sizeof(int);        // 16 KB
    float*  self = (float*)ws;                                                             // 16 KB
    float*  out  = (float*)d_out;

    ln_hash_kernel<<<B * S / 4, 256, 0, stream>>>(x, mask, rot, xmb, bkt, self);
    attn_kernel<<<B * NB * QSPLIT, 256, 0, stream>>>(xmb, bkt, self, out);
}